// Round 1
// baseline (685.394 us; speedup 1.0000x reference)
//
#include <hip/hip_runtime.h>

#define DIM 240
#define NTYPE 10
#define NSLOT 176   // per-type: 64 sum_x + 64 sum_x2 + 32 vec-norm + 16 tens-norm
#define NFEAT 112
#define EPSV 1e-5f

// ws layout (floats):
// [0, 1760)        gAcc   : NTYPE * NSLOT accumulators
// [1760, 1770)     gCnt   : per-type counts (float)
// [1792, 8992)     params : per type t: sub[240], mul[240], bia[240]  (16B aligned)

__global__ __launch_bounds__(256) void zero_kernel(float* __restrict__ ws, int n) {
    int i = blockIdx.x * 256 + threadIdx.x;
    if (i < n) ws[i] = 0.f;
}

__global__ __launch_bounds__(256) void stats_kernel(const float* __restrict__ x,
        const int* __restrict__ type,
        float* __restrict__ gAcc, float* __restrict__ gCnt, int B)
{
    __shared__ float sAcc[NTYPE * NSLOT];
    __shared__ float sCnt[NTYPE];
    const int tid = threadIdx.x;
    for (int i = tid; i < NTYPE * NSLOT; i += 256) sAcc[i] = 0.f;
    if (tid < NTYPE) sCnt[tid] = 0.f;
    __syncthreads();

    // fixed per-thread slot mapping (thread == column within a row)
    int slot = 0; float scale = 1.f; bool isScalar = false;
    const bool active = tid < DIM;
    if (tid < 64)       { slot = tid;                 isScalar = true; }
    else if (tid < 160) { slot = 128 + (tid - 64) / 3;  scale = 1.f / 3.f; }
    else if (tid < 240) { slot = 160 + (tid - 160) / 5; scale = 0.2f; }

    for (int row = blockIdx.x * 2; row < B; row += gridDim.x * 2) {
        const int r1 = row + 1;
        const bool h1 = r1 < B;
        const int t0 = type[row];
        const int t1 = h1 ? type[r1] : 0;
        float v0 = 0.f, v1 = 0.f;
        if (active) {
            v0 = x[(size_t)row * DIM + tid];
            if (h1) v1 = x[(size_t)r1 * DIM + tid];
        }
        if (active) {
            if (isScalar) {
                atomicAdd(&sAcc[t0 * NSLOT + slot],      v0);
                atomicAdd(&sAcc[t0 * NSLOT + 64 + slot], v0 * v0);
                if (h1) {
                    atomicAdd(&sAcc[t1 * NSLOT + slot],      v1);
                    atomicAdd(&sAcc[t1 * NSLOT + 64 + slot], v1 * v1);
                }
            } else {
                atomicAdd(&sAcc[t0 * NSLOT + slot], v0 * v0 * scale);
                if (h1) atomicAdd(&sAcc[t1 * NSLOT + slot], v1 * v1 * scale);
            }
        }
        if (tid == 0) {
            sCnt[t0] += 1.f;
            if (h1) sCnt[t1] += 1.f;
        }
    }
    __syncthreads();
    for (int i = tid; i < NTYPE * NSLOT; i += 256)
        if (sAcc[i] != 0.f) atomicAdd(&gAcc[i], sAcc[i]);
    if (tid < NTYPE && sCnt[tid] != 0.f) atomicAdd(&gCnt[tid], sCnt[tid]);
}

__global__ void finalize_kernel(const float* __restrict__ gAcc,
        const float* __restrict__ gCnt,
        const float* __restrict__ weight, const float* __restrict__ bias,
        float* __restrict__ params)
{
    const int t = blockIdx.x;
    const int c = threadIdx.x;            // 0..239
    const float cnt = fmaxf(gCnt[t], 1.f);
    const float inv = 1.f / cnt;
    float sub = 0.f, mul, bia = 0.f;
    if (c < 64) {
        const float mean = gAcc[t * NSLOT + c] * inv;
        float var = gAcc[t * NSLOT + 64 + c] * inv - mean * mean;
        var = fmaxf(var, 0.f);
        mul = rsqrtf(var + EPSV) * weight[t * NFEAT + c];
        sub = mean;
        bia = bias[t * 64 + c];
    } else if (c < 160) {
        const int ch = (c - 64) / 3;
        const float n = gAcc[t * NSLOT + 128 + ch] * inv;
        mul = rsqrtf(n + EPSV) * weight[t * NFEAT + 64 + ch];
    } else {
        const int ch = (c - 160) / 5;
        const float n = gAcc[t * NSLOT + 160 + ch] * inv;
        mul = rsqrtf(n + EPSV) * weight[t * NFEAT + 96 + ch];
    }
    float* p = params + t * 720;
    p[c]       = sub;
    p[240 + c] = mul;
    p[480 + c] = bia;
}

__global__ __launch_bounds__(256) void apply_kernel(const float* __restrict__ x,
        const int* __restrict__ type, const float* __restrict__ params,
        float* __restrict__ out, int B)
{
    // per type: 60 float4 of sub, 60 of mul, 60 of bias => 180 float4/type
    __shared__ float4 sp[NTYPE * 180];
    const int tid = threadIdx.x;
    const float4* pg = (const float4*)params;
    for (int i = tid; i < NTYPE * 180; i += 256) sp[i] = pg[i];
    __syncthreads();

    const float4* __restrict__ xv = (const float4*)x;
    float4* __restrict__ ov = (float4*)out;
    const unsigned NV = (unsigned)B * 60u;   // 60 float4 per row
    for (unsigned i = blockIdx.x * 256u + tid; i < NV; i += gridDim.x * 256u) {
        const unsigned row = i / 60u;        // magic-mul division
        const unsigned c4  = i - row * 60u;
        const int t = type[row];
        const float4 v = xv[i];
        const float4 s = sp[t * 180 + c4];
        const float4 m = sp[t * 180 + 60 + c4];
        const float4 b = sp[t * 180 + 120 + c4];
        float4 o;
        o.x = (v.x - s.x) * m.x + b.x;
        o.y = (v.y - s.y) * m.y + b.y;
        o.z = (v.z - s.z) * m.z + b.z;
        o.w = (v.w - s.w) * m.w + b.w;
        ov[i] = o;
    }
}

extern "C" void kernel_launch(void* const* d_in, const int* in_sizes, int n_in,
                              void* d_out, int out_size, void* d_ws, size_t ws_size,
                              hipStream_t stream) {
    const float* x      = (const float*)d_in[0];
    const int*   type   = (const int*)d_in[1];
    const float* weight = (const float*)d_in[2];
    const float* bias   = (const float*)d_in[3];
    float* out = (float*)d_out;
    float* ws  = (float*)d_ws;
    const int B = in_sizes[0] / DIM;

    float* gAcc   = ws;
    float* gCnt   = ws + 1760;
    float* params = ws + 1792;

    hipLaunchKernelGGL(zero_kernel, dim3(7), dim3(256), 0, stream, ws, 1792);
    hipLaunchKernelGGL(stats_kernel, dim3(1024), dim3(256), 0, stream,
                       x, type, gAcc, gCnt, B);
    hipLaunchKernelGGL(finalize_kernel, dim3(NTYPE), dim3(240), 0, stream,
                       gAcc, gCnt, weight, bias, params);
    hipLaunchKernelGGL(apply_kernel, dim3(2048), dim3(256), 0, stream,
                       x, type, params, out, B);
}

// Round 3
// 467.326 us; speedup vs baseline: 1.4666x; 1.4666x over previous
//
#include <hip/hip_runtime.h>

#define DIM 240
#define NTYPE 10
#define NFEAT 112
#define NSLOT 176      // per-type: 64 sum_x + 64 sum_x2 + 32 vec + 16 tens
#define PSTRIDE 1792   // per-block partial stride in floats (1770 used)
#define EPSV 1e-5f

// ws layout (floats):
// [0, nblk*PSTRIDE)          per-block partials: [0,1760) slot sums, [1760,1770) counts
// [nblk*PSTRIDE, +7200)      params: per type t: sub[240], mul[240], bia[240]

__global__ __launch_bounds__(256) void stats_kernel(const float* __restrict__ x,
        const int* __restrict__ type, float* __restrict__ partial, int B, int nblk)
{
    const int tid = threadIdx.x;
    const bool active = tid < DIM;
    const bool isScalar = tid < 64;

    float accA[NTYPE], accB[NTYPE];
#pragma unroll
    for (int t = 0; t < NTYPE; t++) { accA[t] = 0.f; accB[t] = 0.f; }

    // counter contribution: inactive lane 255 adds 1.0 per row into accA[ty]
    const float inactAdd = (tid == 255) ? 1.f : 0.f;

    auto accum = [&](int ty, float v) {
        const float v2 = v * v;
        const float addA = active ? (isScalar ? v : v2) : inactAdd;
#pragma unroll
        for (int t = 0; t < NTYPE; t++) {
            if (t == ty) { accA[t] += addA; accB[t] += v2; }  // ty wave-uniform -> scalar branch
        }
    };

    const int stride = nblk * 4;
    for (int row0 = blockIdx.x * 4; row0 + 3 < B; row0 += stride) {
        const int t0 = type[row0], t1 = type[row0 + 1];
        const int t2 = type[row0 + 2], t3 = type[row0 + 3];
        float v0 = 0.f, v1 = 0.f, v2 = 0.f, v3 = 0.f;
        if (active) {
            const float* p = x + (size_t)row0 * DIM + tid;
            v0 = p[0]; v1 = p[DIM]; v2 = p[2 * DIM]; v3 = p[3 * DIM];
        }
        accum(t0, v0); accum(t1, v1); accum(t2, v2); accum(t3, v3);
    }
    // tail rows (B % 4 != 0) -- handled by block 0 only
    if (blockIdx.x == 0) {
        for (int r = B & ~3; r < B; r++) {
            const int ty = type[r];
            float v = active ? x[(size_t)r * DIM + tid] : 0.f;
            accum(ty, v);
        }
    }

    // block-level reduction into slot layout, then non-atomic partial flush
    __shared__ float sAcc[NTYPE * NSLOT + NTYPE];   // 1770
    for (int i = tid; i < NTYPE * NSLOT + NTYPE; i += 256) sAcc[i] = 0.f;
    __syncthreads();

    if (isScalar) {
#pragma unroll
        for (int t = 0; t < NTYPE; t++) {
            sAcc[t * NSLOT + tid] = accA[t];            // exclusive slot: plain store
            sAcc[t * NSLOT + 64 + tid] = accB[t];
        }
    } else if (tid < 160) {
        const int ch = (tid - 64) / 3;
#pragma unroll
        for (int t = 0; t < NTYPE; t++)
            atomicAdd(&sAcc[t * NSLOT + 128 + ch], accA[t]);   // 3-way LDS atomic
    } else if (tid < DIM) {
        const int ch = (tid - 160) / 5;
#pragma unroll
        for (int t = 0; t < NTYPE; t++)
            atomicAdd(&sAcc[t * NSLOT + 160 + ch], accA[t]);   // 5-way LDS atomic
    } else if (tid == 255) {
#pragma unroll
        for (int t = 0; t < NTYPE; t++)
            sAcc[NTYPE * NSLOT + t] = accA[t];          // counts
    }
    __syncthreads();

    float* __restrict__ dst = partial + (size_t)blockIdx.x * PSTRIDE;
    for (int i = tid; i < NTYPE * NSLOT + NTYPE; i += 256) dst[i] = sAcc[i];
}

__global__ __launch_bounds__(256) void finalize_kernel(const float* __restrict__ partial,
        const float* __restrict__ weight, const float* __restrict__ bias,
        float* __restrict__ params, int nblk)
{
    __shared__ float sred[256];
    const int t = blockIdx.x;
    const int c = threadIdx.x;

    // count = sum over blocks of partial[b][1760 + t]
    float cacc = 0.f;
    for (int b = c; b < nblk; b += 256)
        cacc += partial[(size_t)b * PSTRIDE + NTYPE * NSLOT + t];
    sred[c] = cacc;
    __syncthreads();
    for (int s = 128; s > 0; s >>= 1) { if (c < s) sred[c] += sred[c + s]; __syncthreads(); }
    const float cnt = fmaxf(sred[0], 1.f);
    const float inv = 1.f / cnt;

    if (c >= DIM) return;

    float sub = 0.f, mul, bia = 0.f;
    if (c < 64) {
        float S = 0.f, Q = 0.f;
#pragma unroll 4
        for (int b = 0; b < nblk; b++) {
            const float* p = partial + (size_t)b * PSTRIDE + t * NSLOT;
            S += p[c]; Q += p[64 + c];
        }
        const float mean = S * inv;
        float var = Q * inv - mean * mean;
        var = fmaxf(var, 0.f);
        mul = rsqrtf(var + EPSV) * weight[t * NFEAT + c];
        sub = mean;
        bia = bias[t * 64 + c];
    } else if (c < 160) {
        const int ch = (c - 64) / 3;
        float N = 0.f;
#pragma unroll 4
        for (int b = 0; b < nblk; b++)
            N += partial[(size_t)b * PSTRIDE + t * NSLOT + 128 + ch];
        mul = rsqrtf(N * inv * (1.f / 3.f) + EPSV) * weight[t * NFEAT + 64 + ch];
    } else {
        const int ch = (c - 160) / 5;
        float N = 0.f;
#pragma unroll 4
        for (int b = 0; b < nblk; b++)
            N += partial[(size_t)b * PSTRIDE + t * NSLOT + 160 + ch];
        mul = rsqrtf(N * inv * 0.2f + EPSV) * weight[t * NFEAT + 96 + ch];
    }
    float* p = params + t * 720;
    p[c] = sub;
    p[240 + c] = mul;
    p[480 + c] = bia;
}

__global__ __launch_bounds__(256) void apply_kernel(const float* __restrict__ x,
        const int* __restrict__ type, const float* __restrict__ params,
        float* __restrict__ out, int B, int nblocks)
{
    // stage all params in LDS: 10 types * 180 float4 (28.8 KB)
    __shared__ float4 sp[NTYPE * 180];
    const int tid = threadIdx.x;
    const float4* __restrict__ pg = (const float4*)params;
    for (int i = tid; i < NTYPE * 180; i += 256) sp[i] = pg[i];
    __syncthreads();

    const int rBase = tid / 60;          // 0..3 active, 4 for tid>=240
    const int c4 = tid - rBase * 60;
    const bool active = tid < 240;
    const float4* __restrict__ xv = (const float4*)x;
    float4* __restrict__ ov = (float4*)out;

    const int rstride = nblocks * 4;
    for (int row0 = blockIdx.x * 4; row0 < B; row0 += rstride) {
        const int r = row0 + rBase;
        if (active && r < B) {
            const int t = type[r];
            const float4 v = xv[(size_t)r * 60 + c4];
            const float4 s = sp[t * 180 + c4];
            const float4 m = sp[t * 180 + 60 + c4];
            const float4 b = sp[t * 180 + 120 + c4];
            float4 o;
            o.x = (v.x - s.x) * m.x + b.x;
            o.y = (v.y - s.y) * m.y + b.y;
            o.z = (v.z - s.z) * m.z + b.z;
            o.w = (v.w - s.w) * m.w + b.w;
            ov[(size_t)r * 60 + c4] = o;
        }
    }
}

extern "C" void kernel_launch(void* const* d_in, const int* in_sizes, int n_in,
                              void* d_out, int out_size, void* d_ws, size_t ws_size,
                              hipStream_t stream) {
    const float* x      = (const float*)d_in[0];
    const int*   type   = (const int*)d_in[1];
    const float* weight = (const float*)d_in[2];
    const float* bias   = (const float*)d_in[3];
    float* out = (float*)d_out;
    float* ws  = (float*)d_ws;
    const int B = in_sizes[0] / DIM;

    int nblk = 512;
    size_t need_floats = (size_t)nblk * PSTRIDE + 7200;
    if (ws_size < need_floats * 4) {
        nblk = (int)((ws_size / 4 - 7200) / PSTRIDE);
        if (nblk < 1) nblk = 1;
    }
    float* partial = ws;
    float* params  = ws + (size_t)nblk * PSTRIDE;

    hipLaunchKernelGGL(stats_kernel, dim3(nblk), dim3(256), 0, stream,
                       x, type, partial, B, nblk);
    hipLaunchKernelGGL(finalize_kernel, dim3(NTYPE), dim3(256), 0, stream,
                       partial, weight, bias, params, nblk);
    hipLaunchKernelGGL(apply_kernel, dim3(1280), dim3(256), 0, stream,
                       x, type, params, out, B, 1280);
}